// Round 1
// baseline (860.799 us; speedup 1.0000x reference)
//
#include <hip/hip_runtime.h>

#define NN 100000
#define NE 800000
#define HD 64

// ---------------- workspace layout (bytes) ----------------
// flag      : int            @ 0        (256 slot)
// degi      : NN int         @ 256
// cursor    : NN int         @ 256 + 400000
// dinv      : NN float       @ 256 + 800000
// offsets   : (NN+1) int     @ 256 + 1200000
// csr_src   : NE int         @ 256 + 1600256   (aligned)
// total ~ 4.9 MB

__device__ __forceinline__ int load_idx(const void* ei, int i, bool is32) {
    if (is32) return ((const int*)ei)[i];
    return (int)(((const long long*)ei)[i]);
}

// init: degi=1 (self-loop), cursor=0, flag=0
__global__ void k_init(int* degi, int* cursor, int* flag) {
    int i = blockIdx.x * blockDim.x + threadIdx.x;
    if (i < NN) { degi[i] = 1; cursor[i] = 0; }
    if (i == 0) *flag = 0;
}

// detect int32 vs int64 edge indices: read first NE entries as int64.
// If data is really int32, pairs of random node ids combine into values
// >= 2^32 -> out of range -> flag=1 (int32).
__global__ void k_detect(const void* ei, int* flag) {
    int i = blockIdx.x * blockDim.x + threadIdx.x;
    if (i >= NE) return;
    long long v = ((const long long*)ei)[i];
    if (v < 0 || v >= (long long)NN) atomicOr(flag, 1);
}

__global__ void k_count(const void* ei, const int* flag, int* degi) {
    bool is32 = (*flag != 0);
    int e = blockIdx.x * blockDim.x + threadIdx.x;
    if (e >= NE) return;
    int dst = load_idx(ei, NE + e, is32);   // col = edge_index[1]
    atomicAdd(&degi[dst], 1);
}

__global__ void k_dinv(const int* degi, float* dinv) {
    int i = blockIdx.x * blockDim.x + threadIdx.x;
    if (i < NN) dinv[i] = rsqrtf((float)degi[i]);
}

// single-block exclusive scan of (degi[i]-1) -> offsets[0..NN]
__global__ void k_scan(const int* __restrict__ degi, int* __restrict__ offsets) {
    __shared__ int sums[1024];
    int t = threadIdx.x;
    const int chunk = (NN + 1023) / 1024;
    int lo = t * chunk, hi = min(lo + chunk, NN);
    int s = 0;
    for (int i = lo; i < hi; ++i) s += degi[i] - 1;
    sums[t] = s;
    __syncthreads();
    if (t == 0) {
        int run = 0;
        for (int i = 0; i < 1024; ++i) { int v = sums[i]; sums[i] = run; run += v; }
        offsets[NN] = run;   // == NE
    }
    __syncthreads();
    int run = sums[t];
    for (int i = lo; i < hi; ++i) { offsets[i] = run; run += degi[i] - 1; }
}

__global__ void k_scatter(const void* ei, const int* flag,
                          const int* __restrict__ offsets, int* cursor,
                          int* __restrict__ csr_src) {
    bool is32 = (*flag != 0);
    int e = blockIdx.x * blockDim.x + threadIdx.x;
    if (e >= NE) return;
    int src = load_idx(ei, e, is32);        // row = edge_index[0]
    int dst = load_idx(ei, NE + e, is32);
    int p = offsets[dst] + atomicAdd(&cursor[dst], 1);
    csr_src[p] = src;
}

// H[n x 64] = X[n x 64] @ W[64 x 64] (+ bias if BIAS)
template <bool BIAS>
__global__ __launch_bounds__(256) void k_gemm(const float* __restrict__ X,
                                              const float* __restrict__ W,
                                              const float* __restrict__ bias,
                                              float* __restrict__ H, int n) {
    __shared__ float Ws[64 * 64];
    __shared__ float Xs[32 * 64];
    int t = threadIdx.x;
    for (int i = t; i < 64 * 64; i += 256) Ws[i] = W[i];
    int row0 = blockIdx.x * 32;
    for (int i = t; i < 32 * 64; i += 256) {
        int r = row0 + (i >> 6);
        Xs[i] = (r < n) ? X[r * 64 + (i & 63)] : 0.f;
    }
    __syncthreads();
    int c = t & 63, rq = t >> 6;   // wave-uniform rq; Xs reads broadcast
    float acc[8];
#pragma unroll
    for (int rr = 0; rr < 8; ++rr) acc[rr] = 0.f;
    for (int k = 0; k < 64; ++k) {
        float w = Ws[k * 64 + c];
#pragma unroll
        for (int rr = 0; rr < 8; ++rr)
            acc[rr] += Xs[(rq * 8 + rr) * 64 + k] * w;
    }
    float bv = BIAS ? bias[c] : 0.f;
#pragma unroll
    for (int rr = 0; rr < 8; ++rr) {
        int r = row0 + rq * 8 + rr;
        if (r < n) H[r * 64 + c] = acc[rr] + bv;
    }
}

// out[dst] = relu( dinv[dst] * (sum_{e->dst} dinv[src]*H[src] + dinv[dst]*H[dst]) + b )
__global__ __launch_bounds__(256) void k_agg(const float* __restrict__ H,
                                             const int* __restrict__ offsets,
                                             const int* __restrict__ csr_src,
                                             const float* __restrict__ dinv,
                                             const float* __restrict__ b,
                                             float* __restrict__ out) {
    int node = blockIdx.x * 4 + (threadIdx.x >> 6);
    if (node >= NN) return;
    int f = threadIdx.x & 63;
    float dv = dinv[node];
    float acc = dv * H[node * 64 + f];      // self-loop term
    int e0 = offsets[node], e1 = offsets[node + 1];
    for (int e = e0; e < e1; ++e) {
        int s = csr_src[e];
        acc += dinv[s] * H[s * 64 + f];
    }
    float v = acc * dv + b[f];
    out[node * 64 + f] = fmaxf(v, 0.f);
}

extern "C" void kernel_launch(void* const* d_in, const int* in_sizes, int n_in,
                              void* d_out, int out_size, void* d_ws, size_t ws_size,
                              hipStream_t stream) {
    const float* x  = (const float*)d_in[0];
    const void*  ei = d_in[1];               // edge_index, dtype detected on device
    const float* W0 = (const float*)d_in[3];
    const float* b0 = (const float*)d_in[4];
    const float* W1 = (const float*)d_in[5];
    const float* b1 = (const float*)d_in[6];
    const float* W2 = (const float*)d_in[7];
    const float* b2 = (const float*)d_in[8];
    const float* Wl = (const float*)d_in[9];
    const float* bl = (const float*)d_in[10];

    char* ws = (char*)d_ws;
    int*   flag    = (int*)(ws);
    int*   degi    = (int*)(ws + 256);
    int*   cursor  = (int*)(ws + 256 + 400000);
    float* dinv    = (float*)(ws + 256 + 800000);
    int*   offsets = (int*)(ws + 256 + 1200000);
    int*   csr_src = (int*)(ws + 256 + 1600256);

    float* out0 = (float*)d_out;             // first output (layer-3 result)
    float* out1 = out0 + (size_t)NN * HD;    // second output; also GEMM scratch

    const int TB = 256;
    int gN = (NN + TB - 1) / TB;
    int gE = (NE + TB - 1) / TB;
    int gG = (NN + 31) / 32;                 // gemm blocks (32 rows each)
    int gA = (NN + 3) / 4;                   // agg blocks (4 nodes each)

    // ---- graph preprocessing (per-call; inputs restored every launch) ----
    k_init<<<gN, TB, 0, stream>>>(degi, cursor, flag);
    k_detect<<<gE, TB, 0, stream>>>(ei, flag);
    k_count<<<gE, TB, 0, stream>>>(ei, flag, degi);
    k_dinv<<<gN, TB, 0, stream>>>(degi, dinv);
    k_scan<<<1, 1024, 0, stream>>>(degi, offsets);
    k_scatter<<<gE, TB, 0, stream>>>(ei, flag, offsets, cursor, csr_src);

    // ---- layer 0: h = x@W0 -> out1 ; agg+b0+relu -> out0 ----
    k_gemm<false><<<gG, TB, 0, stream>>>(x, W0, nullptr, out1, NN);
    k_agg<<<gA, TB, 0, stream>>>(out1, offsets, csr_src, dinv, b0, out0);
    // ---- layer 1 ----
    k_gemm<false><<<gG, TB, 0, stream>>>(out0, W1, nullptr, out1, NN);
    k_agg<<<gA, TB, 0, stream>>>(out1, offsets, csr_src, dinv, b1, out0);
    // ---- layer 2 ----
    k_gemm<false><<<gG, TB, 0, stream>>>(out0, W2, nullptr, out1, NN);
    k_agg<<<gA, TB, 0, stream>>>(out1, offsets, csr_src, dinv, b2, out0);
    // ---- final linear: out1 = out0@Wl + bl ----
    k_gemm<true><<<gG, TB, 0, stream>>>(out0, Wl, bl, out1, NN);
}

// Round 2
// 568.050 us; speedup vs baseline: 1.5154x; 1.5154x over previous
//
#include <hip/hip_runtime.h>

#define NN 100000
#define NE 800000
#define HD 64

#define SCAN_ELEMS 1024              // elements per scan block
#define SCAN_NB ((NN + SCAN_ELEMS - 1) / SCAN_ELEMS)   // 98

__device__ __forceinline__ int load_idx(const void* ei, int i, bool is32) {
    if (is32) return ((const int*)ei)[i];
    return (int)(((const long long*)ei)[i]);
}

// init: degi=1 (self-loop), cursor=0, flag=0
__global__ void k_init(int* degi, int* cursor, int* flag) {
    int i = blockIdx.x * blockDim.x + threadIdx.x;
    if (i < NN) { degi[i] = 1; cursor[i] = 0; }
    if (i == 0) *flag = 0;
}

// detect int32 vs int64: one block checks the first 4096 int64 slots.
// int64 node ids are all in [0,NN); if the buffer is really int32, a slot is
// (lo | hi<<32) of two random ids -> in-range only if hi==0 (p~1e-5/slot).
__global__ void k_detect(const void* ei, int* flag) {
    __shared__ int bad;
    if (threadIdx.x == 0) bad = 0;
    __syncthreads();
    const long long* p = (const long long*)ei;
    for (int i = threadIdx.x; i < 4096; i += 1024) {
        long long v = p[i];
        if (v < 0 || v >= (long long)NN) bad = 1;
    }
    __syncthreads();
    if (threadIdx.x == 0 && bad) *flag = 1;
}

__global__ void k_count(const void* ei, const int* flag, int* degi) {
    bool is32 = (*flag != 0);
    int e = blockIdx.x * blockDim.x + threadIdx.x;
    if (e >= NE) return;
    int dst = load_idx(ei, NE + e, is32);   // col = edge_index[1]
    atomicAdd(&degi[dst], 1);
}

// ---- parallel scan of (degi[i]-1), 3 phases ----
// A: per-block sums (and fused dinv)
__global__ __launch_bounds__(256) void k_scanA(const int* __restrict__ degi,
                                               float* __restrict__ dinv,
                                               int* __restrict__ bsum) {
    __shared__ int red[256];
    int t = threadIdx.x;
    int base = blockIdx.x * SCAN_ELEMS + t * 4;
    int s = 0;
#pragma unroll
    for (int i = 0; i < 4; ++i) {
        int idx = base + i;
        if (idx < NN) {
            int d = degi[idx];
            s += d - 1;
            dinv[idx] = rsqrtf((float)d);
        }
    }
    red[t] = s;
    __syncthreads();
    for (int off = 128; off > 0; off >>= 1) {
        if (t < off) red[t] += red[t + off];
        __syncthreads();
    }
    if (t == 0) bsum[blockIdx.x] = red[0];
}

// B: serial exclusive scan of the 98 block sums (tiny)
__global__ void k_scanB(int* __restrict__ bsum, int* __restrict__ offsets) {
    if (threadIdx.x != 0) return;
    int run = 0;
    for (int i = 0; i < SCAN_NB; ++i) { int v = bsum[i]; bsum[i] = run; run += v; }
    offsets[NN] = run;   // == NE
}

// C: per-block local exclusive scan + write offsets
__global__ __launch_bounds__(256) void k_scanC(const int* __restrict__ degi,
                                               const int* __restrict__ bsum,
                                               int* __restrict__ offsets) {
    __shared__ int sc[256];
    int t = threadIdx.x;
    int base = blockIdx.x * SCAN_ELEMS + t * 4;
    int v[4];
    int s = 0;
#pragma unroll
    for (int i = 0; i < 4; ++i) {
        int idx = base + i;
        v[i] = (idx < NN) ? degi[idx] - 1 : 0;
        s += v[i];
    }
    sc[t] = s;
    __syncthreads();
    // Hillis-Steele inclusive scan over 256 thread sums
    for (int off = 1; off < 256; off <<= 1) {
        int add = (t >= off) ? sc[t - off] : 0;
        __syncthreads();
        sc[t] += add;
        __syncthreads();
    }
    int run = bsum[blockIdx.x] + sc[t] - s;   // exclusive prefix for this thread
#pragma unroll
    for (int i = 0; i < 4; ++i) {
        int idx = base + i;
        if (idx < NN) offsets[idx] = run;
        run += v[i];
    }
}

__global__ void k_scatter(const void* ei, const int* flag,
                          const int* __restrict__ offsets, int* cursor,
                          int* __restrict__ csr_src) {
    bool is32 = (*flag != 0);
    int e = blockIdx.x * blockDim.x + threadIdx.x;
    if (e >= NE) return;
    int src = load_idx(ei, e, is32);        // row = edge_index[0]
    int dst = load_idx(ei, NE + e, is32);
    int p = offsets[dst] + atomicAdd(&cursor[dst], 1);
    csr_src[p] = src;
}

// H[n x 64] = X[n x 64] @ W[64 x 64] (+ bias if BIAS)
template <bool BIAS>
__global__ __launch_bounds__(256) void k_gemm(const float* __restrict__ X,
                                              const float* __restrict__ W,
                                              const float* __restrict__ bias,
                                              float* __restrict__ H, int n) {
    __shared__ float Ws[64 * 64];
    __shared__ float Xs[32 * 64];
    int t = threadIdx.x;
    for (int i = t; i < 64 * 64; i += 256) Ws[i] = W[i];
    int row0 = blockIdx.x * 32;
    for (int i = t; i < 32 * 64; i += 256) {
        int r = row0 + (i >> 6);
        Xs[i] = (r < n) ? X[r * 64 + (i & 63)] : 0.f;
    }
    __syncthreads();
    int c = t & 63, rq = t >> 6;
    float acc[8];
#pragma unroll
    for (int rr = 0; rr < 8; ++rr) acc[rr] = 0.f;
    for (int k = 0; k < 64; ++k) {
        float w = Ws[k * 64 + c];
#pragma unroll
        for (int rr = 0; rr < 8; ++rr)
            acc[rr] += Xs[(rq * 8 + rr) * 64 + k] * w;
    }
    float bv = BIAS ? bias[c] : 0.f;
#pragma unroll
    for (int rr = 0; rr < 8; ++rr) {
        int r = row0 + rq * 8 + rr;
        if (r < n) H[r * 64 + c] = acc[rr] + bv;
    }
}

// out[dst] = relu( dinv[dst] * (sum_{e->dst} dinv[src]*H[src] + dinv[dst]*H[dst]) + b )
__global__ __launch_bounds__(256) void k_agg(const float* __restrict__ H,
                                             const int* __restrict__ offsets,
                                             const int* __restrict__ csr_src,
                                             const float* __restrict__ dinv,
                                             const float* __restrict__ b,
                                             float* __restrict__ out) {
    int node = blockIdx.x * 4 + (threadIdx.x >> 6);
    if (node >= NN) return;
    int f = threadIdx.x & 63;
    float dv = dinv[node];
    float acc = dv * H[node * 64 + f];      // self-loop term
    int e0 = offsets[node], e1 = offsets[node + 1];
    for (int e = e0; e < e1; ++e) {
        int s = csr_src[e];
        acc += dinv[s] * H[s * 64 + f];
    }
    float v = acc * dv + b[f];
    out[node * 64 + f] = fmaxf(v, 0.f);
}

extern "C" void kernel_launch(void* const* d_in, const int* in_sizes, int n_in,
                              void* d_out, int out_size, void* d_ws, size_t ws_size,
                              hipStream_t stream) {
    const float* x  = (const float*)d_in[0];
    const void*  ei = d_in[1];               // edge_index, dtype detected on device
    const float* W0 = (const float*)d_in[3];
    const float* b0 = (const float*)d_in[4];
    const float* W1 = (const float*)d_in[5];
    const float* b1 = (const float*)d_in[6];
    const float* W2 = (const float*)d_in[7];
    const float* b2 = (const float*)d_in[8];
    const float* Wl = (const float*)d_in[9];
    const float* bl = (const float*)d_in[10];

    char* ws = (char*)d_ws;
    int*   flag    = (int*)(ws);
    int*   degi    = (int*)(ws + 256);
    int*   cursor  = (int*)(ws + 256 + 400000);
    float* dinv    = (float*)(ws + 256 + 800000);
    int*   offsets = (int*)(ws + 256 + 1200000);
    int*   bsum    = (int*)(ws + 256 + 1600256);
    int*   csr_src = (int*)(ws + 256 + 1601280);

    float* out0 = (float*)d_out;             // first output (layer-3 result)
    float* out1 = out0 + (size_t)NN * HD;    // second output; also GEMM scratch

    const int TB = 256;
    int gN = (NN + TB - 1) / TB;
    int gE = (NE + TB - 1) / TB;
    int gG = (NN + 31) / 32;                 // gemm blocks (32 rows each)
    int gA = (NN + 3) / 4;                   // agg blocks (4 nodes each)

    // ---- graph preprocessing ----
    k_init<<<gN, TB, 0, stream>>>(degi, cursor, flag);
    k_detect<<<1, 1024, 0, stream>>>(ei, flag);
    k_count<<<gE, TB, 0, stream>>>(ei, flag, degi);
    k_scanA<<<SCAN_NB, 256, 0, stream>>>(degi, dinv, bsum);
    k_scanB<<<1, 64, 0, stream>>>(bsum, offsets);
    k_scanC<<<SCAN_NB, 256, 0, stream>>>(degi, bsum, offsets);
    k_scatter<<<gE, TB, 0, stream>>>(ei, flag, offsets, cursor, csr_src);

    // ---- layer 0: h = x@W0 -> out1 ; agg+b0+relu -> out0 ----
    k_gemm<false><<<gG, TB, 0, stream>>>(x, W0, nullptr, out1, NN);
    k_agg<<<gA, TB, 0, stream>>>(out1, offsets, csr_src, dinv, b0, out0);
    // ---- layer 1 ----
    k_gemm<false><<<gG, TB, 0, stream>>>(out0, W1, nullptr, out1, NN);
    k_agg<<<gA, TB, 0, stream>>>(out1, offsets, csr_src, dinv, b1, out0);
    // ---- layer 2 ----
    k_gemm<false><<<gG, TB, 0, stream>>>(out0, W2, nullptr, out1, NN);
    k_agg<<<gA, TB, 0, stream>>>(out1, offsets, csr_src, dinv, b2, out0);
    // ---- final linear: out1 = out0@Wl + bl ----
    k_gemm<true><<<gG, TB, 0, stream>>>(out0, Wl, bl, out1, NN);
}

// Round 3
// 451.188 us; speedup vs baseline: 1.9078x; 1.2590x over previous
//
#include <hip/hip_runtime.h>

#define NN 100000
#define NE 800000
#define HD 64

#define SCAN_ELEMS 1024              // elements per scan block
#define SCAN_NB ((NN + SCAN_ELEMS - 1) / SCAN_ELEMS)   // 98

__device__ __forceinline__ int load_idx(const void* ei, int i, bool is32) {
    if (is32) return ((const int*)ei)[i];
    return (int)(((const long long*)ei)[i]);
}

// init: degi=1 (self-loop), cursor=0, flag=0
__global__ void k_init(int* degi, int* cursor, int* flag) {
    int i = blockIdx.x * blockDim.x + threadIdx.x;
    if (i < NN) { degi[i] = 1; cursor[i] = 0; }
    if (i == 0) *flag = 0;
}

// detect int32 vs int64: one block checks the first 4096 int64 slots.
__global__ void k_detect(const void* ei, int* flag) {
    __shared__ int bad;
    if (threadIdx.x == 0) bad = 0;
    __syncthreads();
    const long long* p = (const long long*)ei;
    for (int i = threadIdx.x; i < 4096; i += 1024) {
        long long v = p[i];
        if (v < 0 || v >= (long long)NN) bad = 1;
    }
    __syncthreads();
    if (threadIdx.x == 0 && bad) *flag = 1;
}

__global__ void k_count(const void* ei, const int* flag, int* degi) {
    bool is32 = (*flag != 0);
    int e = blockIdx.x * blockDim.x + threadIdx.x;
    if (e >= NE) return;
    int dst = load_idx(ei, NE + e, is32);   // col = edge_index[1]
    atomicAdd(&degi[dst], 1);
}

// ---- parallel scan of (degi[i]-1), 3 phases ----
__global__ __launch_bounds__(256) void k_scanA(const int* __restrict__ degi,
                                               float* __restrict__ dinv,
                                               int* __restrict__ bsum) {
    __shared__ int red[256];
    int t = threadIdx.x;
    int base = blockIdx.x * SCAN_ELEMS + t * 4;
    int s = 0;
#pragma unroll
    for (int i = 0; i < 4; ++i) {
        int idx = base + i;
        if (idx < NN) {
            int d = degi[idx];
            s += d - 1;
            dinv[idx] = rsqrtf((float)d);
        }
    }
    red[t] = s;
    __syncthreads();
    for (int off = 128; off > 0; off >>= 1) {
        if (t < off) red[t] += red[t + off];
        __syncthreads();
    }
    if (t == 0) bsum[blockIdx.x] = red[0];
}

__global__ void k_scanB(int* __restrict__ bsum, int* __restrict__ offsets) {
    if (threadIdx.x != 0) return;
    int run = 0;
    for (int i = 0; i < SCAN_NB; ++i) { int v = bsum[i]; bsum[i] = run; run += v; }
    offsets[NN] = run;   // == NE
}

__global__ __launch_bounds__(256) void k_scanC(const int* __restrict__ degi,
                                               const int* __restrict__ bsum,
                                               int* __restrict__ offsets) {
    __shared__ int sc[256];
    int t = threadIdx.x;
    int base = blockIdx.x * SCAN_ELEMS + t * 4;
    int v[4];
    int s = 0;
#pragma unroll
    for (int i = 0; i < 4; ++i) {
        int idx = base + i;
        v[i] = (idx < NN) ? degi[idx] - 1 : 0;
        s += v[i];
    }
    sc[t] = s;
    __syncthreads();
    for (int off = 1; off < 256; off <<= 1) {
        int add = (t >= off) ? sc[t - off] : 0;
        __syncthreads();
        sc[t] += add;
        __syncthreads();
    }
    int run = bsum[blockIdx.x] + sc[t] - s;   // exclusive prefix for this thread
#pragma unroll
    for (int i = 0; i < 4; ++i) {
        int idx = base + i;
        if (idx < NN) offsets[idx] = run;
        run += v[i];
    }
}

__global__ void k_scatter(const void* ei, const int* flag,
                          const int* __restrict__ offsets, int* cursor,
                          int* __restrict__ csr_src) {
    bool is32 = (*flag != 0);
    int e = blockIdx.x * blockDim.x + threadIdx.x;
    if (e >= NE) return;
    int src = load_idx(ei, e, is32);        // row = edge_index[0]
    int dst = load_idx(ei, NE + e, is32);
    int p = offsets[dst] + atomicAdd(&cursor[dst], 1);
    csr_src[p] = src;
}

// H[n x 64] = X[n x 64] @ W[64 x 64] (+ bias if BIAS)
template <bool BIAS>
__global__ __launch_bounds__(256) void k_gemm(const float* __restrict__ X,
                                              const float* __restrict__ W,
                                              const float* __restrict__ bias,
                                              float* __restrict__ H, int n) {
    __shared__ float Ws[64 * 64];
    __shared__ float Xs[32 * 64];
    int t = threadIdx.x;
    for (int i = t; i < 64 * 64; i += 256) Ws[i] = W[i];
    int row0 = blockIdx.x * 32;
    for (int i = t; i < 32 * 64; i += 256) {
        int r = row0 + (i >> 6);
        Xs[i] = (r < n) ? X[r * 64 + (i & 63)] : 0.f;
    }
    __syncthreads();
    int c = t & 63, rq = t >> 6;
    float acc[8];
#pragma unroll
    for (int rr = 0; rr < 8; ++rr) acc[rr] = 0.f;
    for (int k = 0; k < 64; ++k) {
        float w = Ws[k * 64 + c];
#pragma unroll
        for (int rr = 0; rr < 8; ++rr)
            acc[rr] += Xs[(rq * 8 + rr) * 64 + k] * w;
    }
    float bv = BIAS ? bias[c] : 0.f;
#pragma unroll
    for (int rr = 0; rr < 8; ++rr) {
        int r = row0 + rq * 8 + rr;
        if (r < n) H[r * 64 + c] = acc[rr] + bv;
    }
}

// Aggregation, 4x edge-parallel per wave:
//   wave = 1 node; 4 groups of 16 lanes; group g loads row of edge e0+g+4k as
//   float4 (16 lanes x 16 B). Cross-group reduce via shfl_xor(16,32); lanes
//   0-15 write the float4 result.
// out[dst] = relu( dv * (sum_e dinv[s]*H[s] + dv*H[dst]) + b )
__global__ __launch_bounds__(256) void k_agg(const float4* __restrict__ H4,
                                             const int* __restrict__ offsets,
                                             const int* __restrict__ csr_src,
                                             const float* __restrict__ dinv,
                                             const float4* __restrict__ b4,
                                             float4* __restrict__ out4) {
    int node = blockIdx.x * 4 + (threadIdx.x >> 6);
    if (node >= NN) return;
    int lane = threadIdx.x & 63;
    int g = lane >> 4;          // edge group 0..3
    int q = lane & 15;          // float4 chunk within the 64-feature row
    float dv = dinv[node];

    float4 acc = make_float4(0.f, 0.f, 0.f, 0.f);
    if (g == 0) {               // self-loop term: dv * H[node]
        float4 h = H4[(size_t)node * 16 + q];
        acc.x = dv * h.x; acc.y = dv * h.y; acc.z = dv * h.z; acc.w = dv * h.w;
    }
    int e0 = offsets[node], e1 = offsets[node + 1];
    for (int e = e0 + g; e < e1; e += 4) {
        int s = csr_src[e];
        float w = dinv[s];
        float4 h = H4[(size_t)s * 16 + q];
        acc.x += w * h.x; acc.y += w * h.y; acc.z += w * h.z; acc.w += w * h.w;
    }
    // reduce the 4 groups (lanes q, q+16, q+32, q+48 hold partials for chunk q)
#pragma unroll
    for (int off = 16; off < 64; off <<= 1) {
        acc.x += __shfl_xor(acc.x, off, 64);
        acc.y += __shfl_xor(acc.y, off, 64);
        acc.z += __shfl_xor(acc.z, off, 64);
        acc.w += __shfl_xor(acc.w, off, 64);
    }
    if (g == 0) {
        float4 bv = b4[q];
        float4 r;
        r.x = fmaxf(acc.x * dv + bv.x, 0.f);
        r.y = fmaxf(acc.y * dv + bv.y, 0.f);
        r.z = fmaxf(acc.z * dv + bv.z, 0.f);
        r.w = fmaxf(acc.w * dv + bv.w, 0.f);
        out4[(size_t)node * 16 + q] = r;
    }
}

extern "C" void kernel_launch(void* const* d_in, const int* in_sizes, int n_in,
                              void* d_out, int out_size, void* d_ws, size_t ws_size,
                              hipStream_t stream) {
    const float* x  = (const float*)d_in[0];
    const void*  ei = d_in[1];               // edge_index, dtype detected on device
    const float* W0 = (const float*)d_in[3];
    const float* b0 = (const float*)d_in[4];
    const float* W1 = (const float*)d_in[5];
    const float* b1 = (const float*)d_in[6];
    const float* W2 = (const float*)d_in[7];
    const float* b2 = (const float*)d_in[8];
    const float* Wl = (const float*)d_in[9];
    const float* bl = (const float*)d_in[10];

    char* ws = (char*)d_ws;
    int*   flag    = (int*)(ws);
    int*   degi    = (int*)(ws + 256);
    int*   cursor  = (int*)(ws + 256 + 400000);
    float* dinv    = (float*)(ws + 256 + 800000);
    int*   offsets = (int*)(ws + 256 + 1200000);
    int*   bsum    = (int*)(ws + 256 + 1600256);
    int*   csr_src = (int*)(ws + 256 + 1601280);

    float* out0 = (float*)d_out;             // first output (layer-3 result)
    float* out1 = out0 + (size_t)NN * HD;    // second output; also GEMM scratch

    const int TB = 256;
    int gN = (NN + TB - 1) / TB;
    int gE = (NE + TB - 1) / TB;
    int gG = (NN + 31) / 32;                 // gemm blocks (32 rows each)
    int gA = (NN + 3) / 4;                   // agg blocks (4 nodes each)

    // ---- graph preprocessing ----
    k_init<<<gN, TB, 0, stream>>>(degi, cursor, flag);
    k_detect<<<1, 1024, 0, stream>>>(ei, flag);
    k_count<<<gE, TB, 0, stream>>>(ei, flag, degi);
    k_scanA<<<SCAN_NB, 256, 0, stream>>>(degi, dinv, bsum);
    k_scanB<<<1, 64, 0, stream>>>(bsum, offsets);
    k_scanC<<<SCAN_NB, 256, 0, stream>>>(degi, bsum, offsets);
    k_scatter<<<gE, TB, 0, stream>>>(ei, flag, offsets, cursor, csr_src);

    // ---- layer 0: h = x@W0 -> out1 ; agg+b0+relu -> out0 ----
    k_gemm<false><<<gG, TB, 0, stream>>>(x, W0, nullptr, out1, NN);
    k_agg<<<gA, TB, 0, stream>>>((const float4*)out1, offsets, csr_src, dinv,
                                 (const float4*)b0, (float4*)out0);
    // ---- layer 1 ----
    k_gemm<false><<<gG, TB, 0, stream>>>(out0, W1, nullptr, out1, NN);
    k_agg<<<gA, TB, 0, stream>>>((const float4*)out1, offsets, csr_src, dinv,
                                 (const float4*)b1, (float4*)out0);
    // ---- layer 2 ----
    k_gemm<false><<<gG, TB, 0, stream>>>(out0, W2, nullptr, out1, NN);
    k_agg<<<gA, TB, 0, stream>>>((const float4*)out1, offsets, csr_src, dinv,
                                 (const float4*)b2, (float4*)out0);
    // ---- final linear: out1 = out0@Wl + bl ----
    k_gemm<true><<<gG, TB, 0, stream>>>(out0, Wl, bl, out1, NN);
}